// Round 10
// baseline (51.966 us; speedup 1.0000x reference)
//
#include <hip/hip_runtime.h>
#include <hip/hip_bf16.h>

// Chamfer via MFMA: D = |x_n - y_m|^2 as augmented K=16 fp16-split GEMM,
// TWO-PASS (rows=outputs in regs, cols staged in LDS; pass 1 swaps roles).
//   a(x) = [xh0..2, xl0..2, xh0..2, 1, 1, xxh, xxl, 0,0,0]
//   b(y) = [-2yh0..2, -2yh0..2, -2yl0..2, yyh, yyl, 1, 1, 0,0,0]
// C layout (verified R3/R5): col=lane&31 -> B pt, row=(r&3)+8*(r>>2)+4*kh -> A pt.
// R10: ONE row-tile per wave + one acc-pair in flight -> live set ~85 regs
// fits arch VGPRs at launch_bounds(256,4). Goal: eliminate the ~30k cyc/SIMD
// of phantom VALU (v_accvgpr moves) betrayed by R9's VGPR_Count=56 vs ~90 live.
// Diagnostic: VGPR_Count should jump to ~90-115 if the theory is right.

typedef _Float16 f16x8 __attribute__((ext_vector_type(8)));
typedef float f32x16 __attribute__((ext_vector_type(16)));

#define NPTS 8192
#define BATCH 8
#define TPB 256
#define BN 128                      // rows per block (4 waves x 1 rowtile x 32)
#define BM 512                      // cols staged per LDS chunk
#define CPB 8                       // chunks per block (half the col space)
#define CTPC (BM / 32)              // 16 col-tiles per chunk
#define NQ_TOT (2 * BATCH * NPTS)   // 131072

__device__ __forceinline__ void cvt_split(float v, _Float16& h, _Float16& l) {
    h = (_Float16)v; l = (_Float16)(v - (float)h);
}

__global__ __launch_bounds__(TPB, 4) void chamfer_mfma_kernel(
    const float* __restrict__ preds, const float* __restrict__ gts,
    float* __restrict__ partial /* [2][BATCH][NPTS][2] */)
{
    __shared__ f16x8 ldsB[CTPC][2][32];   // 16 KB

    const int bid  = blockIdx.x;          // 2048 blocks
    const int pass = bid >> 10;
    const int b       = (bid >> 7) & 7;
    const int rowblk  = (bid >> 1) & 63;  // 64 row-blocks (8192/128)
    const int colhalf = bid & 1;

    const float* __restrict__ Asrc = (pass == 0) ? gts : preds;
    const float* __restrict__ Bsrc = (pass == 0) ? preds : gts;
    const float* __restrict__ Ab = Asrc + (size_t)b * NPTS * 3;
    const float* __restrict__ Bb = Bsrc + (size_t)b * NPTS * 3;

    const int tid  = threadIdx.x;
    const int lane = tid & 63;
    const int w    = tid >> 6;        // 4 waves
    const int kh   = lane >> 5;       // k-half
    const int cl   = lane & 31;       // row (A) / col (B) within tile

    // --- A fragment (1 row-tile per wave) ---
    f16x8 af;
    {
        const int row = rowblk * BN + w * 32 + cl;
        const float* xp = Ab + (size_t)row * 3;
        const float x0 = xp[0], x1 = xp[1], x2 = xp[2];
        _Float16 h0, l0, h1, l1, h2, l2;
        cvt_split(x0, h0, l0); cvt_split(x1, h1, l1); cvt_split(x2, h2, l2);
        const float xx = x0 * x0 + x1 * x1 + x2 * x2;
        _Float16 xxh, xxl; cvt_split(xx, xxh, xxl);
        const f16x8 lo = { h0, h1, h2, l0, l1, l2, h0, h1 };
        const f16x8 hi = { h2, (_Float16)1, (_Float16)1, xxh, xxl,
                           (_Float16)0, (_Float16)0, (_Float16)0 };
        af = kh ? hi : lo;
    }

    const f16x8* __restrict__ bptr = &ldsB[0][kh][cl];
    const f32x16 zc = {};

    float rb[16];
#pragma unroll
    for (int r = 0; r < 16; ++r) rb[r] = 1e30f;

    for (int chunk = 0; chunk < CPB; ++chunk) {
        const int cbase = colhalf * (CPB * BM) + chunk * BM;
        __syncthreads();
        // --- stage+convert BM cols into LDS (2 points per thread) ---
#pragma unroll
        for (int i = 0; i < BM / TPB; ++i) {
            const int pl = i * TPB + tid;
            const float* yp = Bb + (size_t)(cbase + pl) * 3;
            const float y0 = yp[0], y1 = yp[1], y2 = yp[2];
            _Float16 nh0, nl0, nh1, nl1, nh2, nl2;
            { const float hf = (float)(_Float16)y0; nh0 = (_Float16)(-2.f * hf); nl0 = (_Float16)(-2.f * (y0 - hf)); }
            { const float hf = (float)(_Float16)y1; nh1 = (_Float16)(-2.f * hf); nl1 = (_Float16)(-2.f * (y1 - hf)); }
            { const float hf = (float)(_Float16)y2; nh2 = (_Float16)(-2.f * hf); nl2 = (_Float16)(-2.f * (y2 - hf)); }
            const float yy = y0 * y0 + y1 * y1 + y2 * y2;
            _Float16 yyh, yyl; cvt_split(yy, yyh, yyl);
            const f16x8 lo = { nh0, nh1, nh2, nh0, nh1, nh2, nl0, nl1 };
            const f16x8 hi = { nl2, yyh, yyl, (_Float16)1, (_Float16)1,
                               (_Float16)0, (_Float16)0, (_Float16)0 };
            ldsB[pl >> 5][0][pl & 31] = lo;
            ldsB[pl >> 5][1][pl & 31] = hi;
        }
        __syncthreads();

        // --- sweep col-tile PAIRS: 2 ds_read -> 2 MFMA -> 16 min3 ---
#pragma unroll 2
        for (int ct = 0; ct < CTPC; ct += 2) {
            const f16x8 bfA = bptr[ct * 64];
            const f16x8 bfB = bptr[(ct + 1) * 64];
            const f32x16 aA = __builtin_amdgcn_mfma_f32_32x32x16_f16(af, bfA, zc, 0, 0, 0);
            const f32x16 aB = __builtin_amdgcn_mfma_f32_32x32x16_f16(af, bfB, zc, 0, 0, 0);
#pragma unroll
            for (int r = 0; r < 16; ++r)
                rb[r] = fminf(fminf(aA[r], aB[r]), rb[r]);
        }
    }

    // --- reduce row-mins across the 32 cols (lane bits 0..4) ---
#pragma unroll
    for (int r = 0; r < 16; ++r) {
        float v = rb[r];
        v = fminf(v, __shfl_xor(v, 1, 64));
        v = fminf(v, __shfl_xor(v, 2, 64));
        v = fminf(v, __shfl_xor(v, 4, 64));
        v = fminf(v, __shfl_xor(v, 8, 64));
        v = fminf(v, __shfl_xor(v, 16, 64));
        rb[r] = v;
    }

    // C layout: col=lane&31, row=(r&3)+8*(r>>2)+4*(lane>>5)
    if (cl == 0) {
        float* rbase = partial + (((size_t)(pass * BATCH + b) * NPTS)
                     + rowblk * BN + w * 32) * 2 + colhalf;
#pragma unroll
        for (int r = 0; r < 16; ++r) {
            const int rloc = (r & 3) + 8 * (r >> 2) + 4 * kh;
            rbase[rloc * 2] = rb[r];
        }
    }
}

// Stage 2: min the two col-half partials per query, sum -> 512 block sums
__global__ __launch_bounds__(256) void chamfer_reduce1(
    const float* __restrict__ partial, float* __restrict__ bsums)
{
    const int gid = blockIdx.x * 256 + threadIdx.x;   // one query per thread
    const float2 v = ((const float2*)partial)[gid];
    float m = fminf(v.x, v.y);

#pragma unroll
    for (int off = 32; off > 0; off >>= 1) m += __shfl_down(m, off, 64);

    __shared__ float wsum[4];
    const int lane = threadIdx.x & 63;
    const int wid  = threadIdx.x >> 6;
    if (lane == 0) wsum[wid] = m;
    __syncthreads();
    if (threadIdx.x == 0)
        bsums[blockIdx.x] = (wsum[0] + wsum[1]) + (wsum[2] + wsum[3]);
}

// Stage 3: sum 512 block sums, scale, write scalar
__global__ __launch_bounds__(512) void chamfer_reduce2(
    const float* __restrict__ bsums, float* __restrict__ out)
{
    float m = bsums[threadIdx.x];
#pragma unroll
    for (int off = 32; off > 0; off >>= 1) m += __shfl_down(m, off, 64);

    __shared__ float wsum[8];
    const int lane = threadIdx.x & 63;
    const int wid  = threadIdx.x >> 6;
    if (lane == 0) wsum[wid] = m;
    __syncthreads();
    if (threadIdx.x == 0) {
        float t = ((wsum[0] + wsum[1]) + (wsum[2] + wsum[3]))
                + ((wsum[4] + wsum[5]) + (wsum[6] + wsum[7]));
        out[0] = t * (1.0f / 65536.0f);
    }
}

extern "C" void kernel_launch(void* const* d_in, const int* in_sizes, int n_in,
                              void* d_out, int out_size, void* d_ws, size_t ws_size,
                              hipStream_t stream) {
    const float* preds = (const float*)d_in[0];   // [8, 8192, 3]
    const float* gts   = (const float*)d_in[1];   // [8, 8192, 3]
    float* out = (float*)d_out;

    float* partial = (float*)d_ws;   // 131072*2 floats = 1 MB, fully overwritten
    float* bsums   = (float*)((char*)d_ws + (size_t)NQ_TOT * 2 * sizeof(float));

    chamfer_mfma_kernel<<<2048, TPB, 0, stream>>>(preds, gts, partial);
    chamfer_reduce1<<<512, 256, 0, stream>>>(partial, bsums);
    chamfer_reduce2<<<1, 512, 0, stream>>>(bsums, out);
}

// Round 11
// 48.521 us; speedup vs baseline: 1.0710x; 1.0710x over previous
//
#include <hip/hip_runtime.h>
#include <hip/hip_bf16.h>

// Chamfer via MFMA: D = |x_n - y_m|^2 as augmented K=16 fp16-split GEMM.
//   a(x) = [xh0..2, xl0..2, xh0..2, 1, 1, xxh, xxl, 0,0,0]
//   b(y) = [-2yh0..2, -2yh0..2, -2yl0..2, yyh, yyl, 1, 1, 0,0,0]
// C layout (verified R3/R5): col=lane&31 -> B pt, row=(r&3)+8*(r>>2)+4*kh -> A pt.
// R11 = R3 (launch_bounds(256,2): the ONLY config with no phantom VALU --
// 256-reg budget keeps MFMA accs out of the AGPR bank) plus:
//  * min3 pairing: fold TWO col-tiles per slot (8 VALU/MFMA, the fold floor)
//  * double-buffered LDS (2x16KB) + register prefetch of next chunk's points:
//    one barrier per chunk, global latency hidden under MFMA phase
//  * grid 512 = 2 blocks/CU so barrier stalls interleave
// Each block: 256 rows x all 8192 cols (16 chunks of 512) -> rowmin direct.

typedef _Float16 f16x8 __attribute__((ext_vector_type(8)));
typedef float f32x16 __attribute__((ext_vector_type(16)));

#define NPTS 8192
#define BATCH 8
#define TPB 256
#define BN 256                      // rows per block (4 waves x 2 rowtiles x 32)
#define CHUNK 512                   // cols per LDS chunk
#define NCH (NPTS / CHUNK)          // 16
#define CTPC (CHUNK / 32)           // 16 col-tiles per chunk
#define NQ_TOT (2 * BATCH * NPTS)   // 131072

__device__ __forceinline__ void cvt_split(float v, _Float16& h, _Float16& l) {
    h = (_Float16)v; l = (_Float16)(v - (float)h);
}

__global__ __launch_bounds__(TPB, 2) void chamfer_mfma_kernel(
    const float* __restrict__ preds, const float* __restrict__ gts,
    float* __restrict__ rowmin /* [2][BATCH][NPTS] */)
{
    __shared__ f16x8 ldsB[2][CTPC][2][32];   // 32 KB (two 16 KB buffers)

    const int bid  = blockIdx.x;          // 512 blocks
    const int pass = bid >> 8;
    const int b      = (bid >> 5) & 7;
    const int rowblk = bid & 31;          // 32 row-blocks (8192/256)

    const float* __restrict__ Asrc = (pass == 0) ? gts : preds;
    const float* __restrict__ Bsrc = (pass == 0) ? preds : gts;
    const float* __restrict__ Ab = Asrc + (size_t)b * NPTS * 3;
    const float* __restrict__ Bb = Bsrc + (size_t)b * NPTS * 3;

    const int tid  = threadIdx.x;
    const int lane = tid & 63;
    const int w    = tid >> 6;        // 4 waves
    const int kh   = lane >> 5;       // k-half
    const int cl   = lane & 31;       // row (A) / col (B) within tile

    // --- A fragments (2 row-tiles per wave) ---
    f16x8 af[2];
#pragma unroll
    for (int t = 0; t < 2; ++t) {
        const int row = rowblk * BN + w * 64 + t * 32 + cl;
        const float* xp = Ab + (size_t)row * 3;
        const float x0 = xp[0], x1 = xp[1], x2 = xp[2];
        _Float16 h0, l0, h1, l1, h2, l2;
        cvt_split(x0, h0, l0); cvt_split(x1, h1, l1); cvt_split(x2, h2, l2);
        const float xx = x0 * x0 + x1 * x1 + x2 * x2;
        _Float16 xxh, xxl; cvt_split(xx, xxh, xxl);
        const f16x8 lo = { h0, h1, h2, l0, l1, l2, h0, h1 };
        const f16x8 hi = { h2, (_Float16)1, (_Float16)1, xxh, xxl,
                           (_Float16)0, (_Float16)0, (_Float16)0 };
        af[t] = kh ? hi : lo;
    }

    const f32x16 zc = {};
    float rb[2][16];
#pragma unroll
    for (int t = 0; t < 2; ++t)
#pragma unroll
        for (int r = 0; r < 16; ++r) rb[t][r] = 1e30f;

    // --- staging helper (2 points per thread per chunk) ---
    auto stage = [&](int buf, float y00, float y01, float y02,
                     float y10, float y11, float y12) {
#pragma unroll
        for (int i = 0; i < 2; ++i) {
            const float y0 = i ? y10 : y00;
            const float y1 = i ? y11 : y01;
            const float y2 = i ? y12 : y02;
            const int pl = i * TPB + tid;
            _Float16 nh0, nl0, nh1, nl1, nh2, nl2;
            { const float hf = (float)(_Float16)y0; nh0 = (_Float16)(-2.f * hf); nl0 = (_Float16)(-2.f * (y0 - hf)); }
            { const float hf = (float)(_Float16)y1; nh1 = (_Float16)(-2.f * hf); nl1 = (_Float16)(-2.f * (y1 - hf)); }
            { const float hf = (float)(_Float16)y2; nh2 = (_Float16)(-2.f * hf); nl2 = (_Float16)(-2.f * (y2 - hf)); }
            const float yy = y0 * y0 + y1 * y1 + y2 * y2;
            _Float16 yyh, yyl; cvt_split(yy, yyh, yyl);
            const f16x8 lo = { nh0, nh1, nh2, nh0, nh1, nh2, nl0, nl1 };
            const f16x8 hi = { nl2, yyh, yyl, (_Float16)1, (_Float16)1,
                               (_Float16)0, (_Float16)0, (_Float16)0 };
            ldsB[buf][pl >> 5][0][pl & 31] = lo;
            ldsB[buf][pl >> 5][1][pl & 31] = hi;
        }
    };

    // --- prologue: stage chunk 0 into buffer 0 ---
    {
        const float* yp0 = Bb + (size_t)tid * 3;
        const float* yp1 = yp0 + (size_t)TPB * 3;
        stage(0, yp0[0], yp0[1], yp0[2], yp1[0], yp1[1], yp1[2]);
    }
    __syncthreads();

    for (int c = 0; c < NCH; ++c) {
        // prefetch next chunk's points into registers (hides HBM latency)
        float g0 = 0.f, g1 = 0.f, g2 = 0.f, g3 = 0.f, g4 = 0.f, g5 = 0.f;
        if (c + 1 < NCH) {
            const float* yp0 = Bb + (size_t)((c + 1) * CHUNK + tid) * 3;
            const float* yp1 = yp0 + (size_t)TPB * 3;
            g0 = yp0[0]; g1 = yp0[1]; g2 = yp0[2];
            g3 = yp1[0]; g4 = yp1[1]; g5 = yp1[2];
        }

        // --- sweep col-tile PAIRS: 2 ds_read -> 4 MFMA -> 32 min3 ---
        const f16x8* __restrict__ bptr = &ldsB[c & 1][0][kh][cl];
#pragma unroll 2
        for (int ct = 0; ct < CTPC; ct += 2) {
            const f16x8 bfA = bptr[ct * 64];
            const f16x8 bfB = bptr[(ct + 1) * 64];
#pragma unroll
            for (int t = 0; t < 2; ++t) {
                const f32x16 aA = __builtin_amdgcn_mfma_f32_32x32x16_f16(af[t], bfA, zc, 0, 0, 0);
                const f32x16 aB = __builtin_amdgcn_mfma_f32_32x32x16_f16(af[t], bfB, zc, 0, 0, 0);
#pragma unroll
                for (int r = 0; r < 16; ++r)
                    rb[t][r] = fminf(fminf(aA[r], aB[r]), rb[t][r]);
            }
        }

        // convert + write prefetched points into the other buffer
        if (c + 1 < NCH) stage((c + 1) & 1, g0, g1, g2, g3, g4, g5);
        __syncthreads();
    }

    // --- reduce row-mins across the 32 cols (lane bits 0..4) ---
#pragma unroll
    for (int t = 0; t < 2; ++t)
#pragma unroll
        for (int r = 0; r < 16; ++r) {
            float v = rb[t][r];
            v = fminf(v, __shfl_xor(v, 1, 64));
            v = fminf(v, __shfl_xor(v, 2, 64));
            v = fminf(v, __shfl_xor(v, 4, 64));
            v = fminf(v, __shfl_xor(v, 8, 64));
            v = fminf(v, __shfl_xor(v, 16, 64));
            rb[t][r] = v;
        }

    // C layout: col=lane&31, row=(r&3)+8*(r>>2)+4*(lane>>5)
    if (cl == 0) {
        float* rbase = rowmin + (size_t)(pass * BATCH + b) * NPTS
                     + rowblk * BN + w * 64;
#pragma unroll
        for (int t = 0; t < 2; ++t)
#pragma unroll
            for (int r = 0; r < 16; ++r) {
                const int rloc = (r & 3) + 8 * (r >> 2) + 4 * kh;
                rbase[t * 32 + rloc] = rb[t][r];
            }
    }
}

// Stage 2: sum 131072 row-mins -> 512 block sums
__global__ __launch_bounds__(256) void chamfer_reduce1(
    const float* __restrict__ rowmin, float* __restrict__ bsums)
{
    const int gid = blockIdx.x * 256 + threadIdx.x;
    float m = rowmin[gid];
#pragma unroll
    for (int off = 32; off > 0; off >>= 1) m += __shfl_down(m, off, 64);

    __shared__ float wsum[4];
    const int lane = threadIdx.x & 63;
    const int wid  = threadIdx.x >> 6;
    if (lane == 0) wsum[wid] = m;
    __syncthreads();
    if (threadIdx.x == 0)
        bsums[blockIdx.x] = (wsum[0] + wsum[1]) + (wsum[2] + wsum[3]);
}

// Stage 3: sum 512 block sums, scale, write scalar
__global__ __launch_bounds__(512) void chamfer_reduce2(
    const float* __restrict__ bsums, float* __restrict__ out)
{
    float m = bsums[threadIdx.x];
#pragma unroll
    for (int off = 32; off > 0; off >>= 1) m += __shfl_down(m, off, 64);

    __shared__ float wsum[8];
    const int lane = threadIdx.x & 63;
    const int wid  = threadIdx.x >> 6;
    if (lane == 0) wsum[wid] = m;
    __syncthreads();
    if (threadIdx.x == 0) {
        float t = ((wsum[0] + wsum[1]) + (wsum[2] + wsum[3]))
                + ((wsum[4] + wsum[5]) + (wsum[6] + wsum[7]));
        out[0] = t * (1.0f / 65536.0f);
    }
}

extern "C" void kernel_launch(void* const* d_in, const int* in_sizes, int n_in,
                              void* d_out, int out_size, void* d_ws, size_t ws_size,
                              hipStream_t stream) {
    const float* preds = (const float*)d_in[0];   // [8, 8192, 3]
    const float* gts   = (const float*)d_in[1];   // [8, 8192, 3]
    float* out = (float*)d_out;

    float* rowmin = (float*)d_ws;   // 131072 floats = 512 KB, fully overwritten
    float* bsums  = (float*)((char*)d_ws + (size_t)NQ_TOT * sizeof(float));

    chamfer_mfma_kernel<<<512, TPB, 0, stream>>>(preds, gts, rowmin);
    chamfer_reduce1<<<512, 256, 0, stream>>>(rowmin, bsums);
    chamfer_reduce2<<<1, 512, 0, stream>>>(bsums, out);
}